// Round 10
// baseline (161.132 us; speedup 1.0000x reference)
//
#include <hip/hip_runtime.h>
#include <math.h>

#define N 4096
#define NFEAT 512
#define NHID 64
#define NCLASS 16
#define NHEADS 8
#define ALPHA 0.2f
#define NC 256   // chunks per head (16 rows each)

typedef __attribute__((ext_vector_type(8))) short bf16x8;
typedef __attribute__((ext_vector_type(4))) float f32x4;

__device__ inline unsigned short f2bf(float f) {
  unsigned u = __float_as_uint(f);
  unsigned r = u + 0x7fffu + ((u >> 16) & 1u);  // RNE
  return (unsigned short)(r >> 16);
}
__device__ inline float bf2f(unsigned short u) {
  return __uint_as_float(((unsigned)u) << 16);
}
__device__ inline unsigned mono(float f) {
  unsigned u = __float_as_uint(f);
  return (u & 0x80000000u) ? ~u : (u | 0x80000000u);
}

// ---------------------------------------------------------------------------
// P0: pack. blocks [0,2048): x->bf16; [2048,2112): Wt=bf16(Wh^T); 2112: Wt2.
// ---------------------------------------------------------------------------
__global__ __launch_bounds__(256) void k_pack(const float* __restrict__ x,
                                              const float* __restrict__ Wh,
                                              const float* __restrict__ Wo,
                                              unsigned short* __restrict__ xb,
                                              unsigned short* __restrict__ Wt,
                                              unsigned short* __restrict__ Wt2) {
  int b = blockIdx.x;
  if (b < 2048) {
    int i = (b * 256 + threadIdx.x) * 4;
    float4 v = *(const float4*)(x + i);
    ushort4 o;
    o.x = f2bf(v.x); o.y = f2bf(v.y); o.z = f2bf(v.z); o.w = f2bf(v.w);
    *(ushort4*)(xb + i) = o;
  } else if (b < 2112) {
    int idx = b - 2048;
    int kt = idx & 7, hd = idx >> 3;
    __shared__ float ld[64][65];
    const float* src = Wh + ((size_t)hd * NFEAT + kt * 64) * NHID;
    int r = threadIdx.x >> 2, c0 = (threadIdx.x & 3) * 16;
#pragma unroll
    for (int j = 0; j < 4; ++j) {
      float4 v = *(const float4*)(src + (size_t)r * NHID + c0 + j * 4);
      ld[r][c0 + j * 4 + 0] = v.x; ld[r][c0 + j * 4 + 1] = v.y;
      ld[r][c0 + j * 4 + 2] = v.z; ld[r][c0 + j * 4 + 3] = v.w;
    }
    __syncthreads();
    int n = threadIdx.x >> 2, kq = threadIdx.x & 3;
    unsigned short tmp[16];
#pragma unroll
    for (int j = 0; j < 16; ++j) tmp[j] = f2bf(ld[kq * 16 + j][n]);
    unsigned short* dst = Wt + ((size_t)hd * 64 + n) * NFEAT + kt * 64 + kq * 16;
    ((uint4*)dst)[0] = *(uint4*)tmp;
    ((uint4*)dst)[1] = *(uint4*)(tmp + 8);
  } else {
    for (int e = threadIdx.x; e < NFEAT * NCLASS; e += 256) {
      int n = e & 15, k = e >> 4;
      Wt2[(size_t)n * NFEAT + k] = f2bf(Wo[(size_t)k * NCLASS + n]);
    }
  }
}

// ---------------------------------------------------------------------------
// K1: MFMA bf16 GEMM h = x @ Wh per head, 128x64 tile, 4 waves, fused scores.
// h stored bf16.
// ---------------------------------------------------------------------------
__global__ __launch_bounds__(256) void k_gemm_h(const unsigned short* __restrict__ xb,
                                                const unsigned short* __restrict__ Wt,
                                                const float* __restrict__ ah,
                                                unsigned short* __restrict__ h1b,
                                                float* __restrict__ ssrc,
                                                float* __restrict__ sdst) {
  const int hd = blockIdx.y;
  const int i0 = blockIdx.x * 128;
  const int t = threadIdx.x;
  const int w = t >> 6, lane = t & 63;
  const int lr = lane & 15, kg = lane >> 4;
  const int wm = (w & 1) * 64, wn = (w >> 1) * 32;
  __shared__ uint4 Als[128][4];
  __shared__ uint4 Bls[64][4];
  __shared__ float sredS[128][2];
  __shared__ float sredD[128][2];
  const unsigned short* xrow = xb + (size_t)i0 * NFEAT;
  const unsigned short* wrow = Wt + (size_t)hd * 64 * NFEAT;

  f32x4 acc[4][2];
#pragma unroll
  for (int a = 0; a < 4; ++a)
#pragma unroll
    for (int b = 0; b < 2; ++b) acc[a][b] = (f32x4){0.f, 0.f, 0.f, 0.f};

  const int ra = t >> 1, ua = (t & 1) * 2;
  const int rb = t >> 2, ub = t & 3;
  for (int k0 = 0; k0 < NFEAT; k0 += 32) {
    uint4 qa0 = *(const uint4*)(xrow + (size_t)ra * NFEAT + k0 + ua * 8);
    uint4 qa1 = *(const uint4*)(xrow + (size_t)ra * NFEAT + k0 + ua * 8 + 8);
    uint4 qb  = *(const uint4*)(wrow + (size_t)rb * NFEAT + k0 + ub * 8);
    Als[ra][(ua) ^ (ra & 3)] = qa0;
    Als[ra][(ua + 1) ^ (ra & 3)] = qa1;
    Bls[rb][ub ^ (rb & 3)] = qb;
    __syncthreads();
    bf16x8 af[4], bfv[2];
#pragma unroll
    for (int mb = 0; mb < 4; ++mb) {
      int row = wm + mb * 16 + lr;
      af[mb] = __builtin_bit_cast(bf16x8, Als[row][kg ^ (row & 3)]);
    }
#pragma unroll
    for (int nb = 0; nb < 2; ++nb) {
      int col = wn + nb * 16 + lr;
      bfv[nb] = __builtin_bit_cast(bf16x8, Bls[col][kg ^ (col & 3)]);
    }
#pragma unroll
    for (int mb = 0; mb < 4; ++mb)
#pragma unroll
      for (int nb = 0; nb < 2; ++nb)
        acc[mb][nb] = __builtin_amdgcn_mfma_f32_16x16x32_bf16(af[mb], bfv[nb], acc[mb][nb], 0, 0, 0);
    __syncthreads();
  }

  unsigned short* hout = h1b + ((size_t)hd * N + i0) * NHID;
#pragma unroll
  for (int mb = 0; mb < 4; ++mb)
#pragma unroll
    for (int nb = 0; nb < 2; ++nb) {
      int rbase = wm + mb * 16 + kg * 4;
      int col = wn + nb * 16 + lr;
#pragma unroll
      for (int reg = 0; reg < 4; ++reg)
        hout[(size_t)(rbase + reg) * NHID + col] = f2bf(acc[mb][nb][reg]);
    }

  float aS[2], aD[2];
#pragma unroll
  for (int nb = 0; nb < 2; ++nb) {
    aS[nb] = ah[hd * 128 + wn + nb * 16 + lr];
    aD[nb] = ah[hd * 128 + 64 + wn + nb * 16 + lr];
  }
#pragma unroll
  for (int mb = 0; mb < 4; ++mb)
#pragma unroll
    for (int reg = 0; reg < 4; ++reg) {
      float ps = acc[mb][0][reg] * aS[0] + acc[mb][1][reg] * aS[1];
      float pd = acc[mb][0][reg] * aD[0] + acc[mb][1][reg] * aD[1];
#pragma unroll
      for (int m = 1; m < 16; m <<= 1) { ps += __shfl_xor(ps, m); pd += __shfl_xor(pd, m); }
      if (lr == 0) {
        int rl = wm + mb * 16 + kg * 4 + reg;
        sredS[rl][w >> 1] = ps;
        sredD[rl][w >> 1] = pd;
      }
    }
  __syncthreads();
  if (t < 128) {
    ssrc[(size_t)hd * N + i0 + t] = sredS[t][0] + sredS[t][1];
    sdst[(size_t)hd * N + i0 + t] = sredD[t][0] + sredD[t][1];
  }
}

// ---------------------------------------------------------------------------
// K4: ballot rank + per-row split-k (layer 1 only). u32 keys.
// ---------------------------------------------------------------------------
__global__ __launch_bounds__(256) void k_rank(const float* __restrict__ t,
                                              const float* __restrict__ ssrc,
                                              float* __restrict__ ts,
                                              int* __restrict__ perm,
                                              int* __restrict__ ksp) {
  int hd = blockIdx.y;
  const float* th = t + (size_t)hd * N;
  __shared__ unsigned skey[N];
  int tid = threadIdx.x;
  for (int i = tid; i < N; i += 256)
    skey[i] = (mono(th[i]) & 0xFFFFF000u) | (unsigned)i;
  __syncthreads();
  int wv = tid >> 6, lane = tid & 63;
  int jbase = blockIdx.x * 64 + wv * 16;
  unsigned kj[16], qk[16];
  int cnt[16], cq[16];
#pragma unroll
  for (int jj = 0; jj < 16; ++jj) {
    kj[jj] = skey[jbase + jj];
    qk[jj] = (mono(-ssrc[(size_t)hd * N + jbase + jj]) & 0xFFFFF000u) | 0xFFFu;
    cnt[jj] = 0; cq[jj] = 0;
  }
  for (int c = 0; c < N; c += 64) {
    unsigned key = skey[c + lane];
#pragma unroll
    for (int jj = 0; jj < 16; ++jj) {
      cnt[jj] += __popcll(__ballot(key < kj[jj]));
      cq[jj]  += __popcll(__ballot(key < qk[jj]));
    }
  }
  int myc = 0, myq = 0;
#pragma unroll
  for (int jj = 0; jj < 16; ++jj)
    if (lane == jj) { myc = cnt[jj]; myq = cq[jj]; }
  if (lane < 16) {
    int j = jbase + lane;
    ts[(size_t)hd * N + myc] = th[j];
    perm[(size_t)hd * N + myc] = j;
    ksp[(size_t)hd * N + j] = myq;
  }
}

// ---------------------------------------------------------------------------
// K5a: chunksum layer 1 (wide grid for the gather). One wave per 16-row
// chunk; grid (64, 8) x 256 thr = 2048 waves.
// ---------------------------------------------------------------------------
__global__ __launch_bounds__(256) void k_chunksum1(const float* __restrict__ ts,
                                                   const int* __restrict__ perm,
                                                   const unsigned short* __restrict__ h1b,
                                                   float* __restrict__ csA,
                                                   float* __restrict__ csB,
                                                   float* __restrict__ csAz,
                                                   float* __restrict__ csBz) {
  int hd = blockIdx.y, lane = threadIdx.x & 63;
  int c = blockIdx.x * 4 + (threadIdx.x >> 6);
  int r0 = c * 16;
  float tm = ts[(size_t)hd * N + N - 1];
  float tvv = ts[(size_t)hd * N + r0 + (lane & 15)];
  float ev = expf((lane < 16 ? ALPHA : 1.f) * (tvv - tm));
  int pvv = perm[(size_t)hd * N + r0 + (lane & 15)];
  float sA = 0.f, sB = 0.f, zA = 0.f, zB = 0.f;
#pragma unroll
  for (int r = 0; r < 16; ++r) {
    float eA = __shfl(ev, r);
    float eB = __shfl(ev, 16 + r);
    int p = __shfl(pvv, r);
    float hv = bf2f(h1b[((size_t)hd * N + p) * NHID + lane]);
    sA += eA * hv; sB += eB * hv; zA += eA; zB += eB;
  }
  csA[((size_t)hd * NC + c) * NHID + lane] = sA;
  csB[((size_t)hd * NC + c) * NHID + lane] = sB;
  if (lane == 0) { csAz[hd * NC + c] = zA; csBz[hd * NC + c] = zB; }
}

// ---------------------------------------------------------------------------
// K5b: scan-only layer 1 (narrow; no gather). 8 blocks x 1024 thr.
// ---------------------------------------------------------------------------
__global__ __launch_bounds__(1024) void k_chunkscan1(float* __restrict__ csA,
                                                     float* __restrict__ csB,
                                                     float* __restrict__ csAz,
                                                     float* __restrict__ csBz) {
  int hd = blockIdx.x;
  int t = threadIdx.x, w = t >> 6, lane = t & 63;
  __shared__ float pA[16][64], pB[16][64];
  __shared__ float pAz[16], pBz[16];
  float rA[16], rB[16], rAz[16], rBz[16];
#pragma unroll
  for (int cc = 0; cc < 16; ++cc) {
    int c = w * 16 + cc;
    rA[cc] = csA[((size_t)hd * NC + c) * NHID + lane];
    rB[cc] = csB[((size_t)hd * NC + c) * NHID + lane];
    rAz[cc] = csAz[hd * NC + c];
    rBz[cc] = csBz[hd * NC + c];
  }
  float tA = 0.f, tB = 0.f, tAz = 0.f, tBz = 0.f;
#pragma unroll
  for (int cc = 0; cc < 16; ++cc) { tA += rA[cc]; tB += rB[cc]; tAz += rAz[cc]; tBz += rBz[cc]; }
  pA[w][lane] = tA; pB[w][lane] = tB;
  if (lane == 0) { pAz[w] = tAz; pBz[w] = tBz; }
  __syncthreads();
  float bA = 0.f, bAz = 0.f, bB = 0.f, bBz = 0.f;
  for (int w2 = 0; w2 < w; ++w2) { bA += pA[w2][lane]; bAz += pAz[w2]; }
  for (int w2 = w + 1; w2 < 16; ++w2) { bB += pB[w2][lane]; bBz += pBz[w2]; }
  float run = bA, runz = bAz;
#pragma unroll
  for (int cc = 0; cc < 16; ++cc) {
    int c = w * 16 + cc;
    csA[((size_t)hd * NC + c) * NHID + lane] = run; run += rA[cc];
    if (lane == 0) csAz[hd * NC + c] = runz;
    runz += rAz[cc];
  }
  run = bB; runz = bBz;
#pragma unroll
  for (int cc = 15; cc >= 0; --cc) {
    int c = w * 16 + cc;
    csB[((size_t)hd * NC + c) * NHID + lane] = run; run += rB[cc];
    if (lane == 0) csBz[hd * NC + c] = runz;
    runz += rBz[cc];
  }
}

// ---------------------------------------------------------------------------
// K6: layer-1 combine. Precomputed split-k; chunk bases + 16-term rebuild.
// ---------------------------------------------------------------------------
__global__ __launch_bounds__(256) void k_combine1(const float* __restrict__ ssrc,
                                                  const float* __restrict__ ts,
                                                  const int* __restrict__ perm,
                                                  const int* __restrict__ ksp,
                                                  const unsigned short* __restrict__ h1b,
                                                  const float* __restrict__ csA,
                                                  const float* __restrict__ csB,
                                                  const float* __restrict__ csAz,
                                                  const float* __restrict__ csBz,
                                                  unsigned short* __restrict__ xcb) {
  int hd = blockIdx.x >> 8;
  int base = (blockIdx.x & 255) * 16;
  int w = threadIdx.x >> 6, lane = threadIdx.x & 63;
  const float* tsh = ts + (size_t)hd * N;
  float tm = tsh[N - 1];
  for (int it = 0; it < 4; ++it) {
    int i = base + w * 4 + it;
    float s = ssrc[(size_t)hd * N + i];
    int k = ksp[(size_t)hd * N + i];
    int c = k >> 4; if (c > NC - 1) c = NC - 1;
    int c0 = c * 16;
    float v = s + tm;
    float m = fmaxf(v, ALPHA * v);
    float wA = expf(ALPHA * v - m), wB = expf(v - m);
    size_t cb = (size_t)hd * NC + c;
    float numA = csA[cb * NHID + lane];
    float numB = csB[cb * NHID + lane];
    float zA = csAz[cb], zB = csBz[cb];
    int r15 = lane & 15;
    float tvv = tsh[c0 + r15];
    int pvv = perm[(size_t)hd * N + c0 + r15];
    float ev = expf(((c0 + r15) < k ? ALPHA : 1.f) * (tvv - tm));
#pragma unroll
    for (int r = 0; r < 16; ++r) {
      float e = __shfl(ev, r);
      int p = __shfl(pvv, r);
      float hv = bf2f(h1b[((size_t)hd * N + p) * NHID + lane]);
      bool isA = (c0 + r) < k;
      if (isA) { numA += e * hv; zA += e; } else { numB += e * hv; zB += e; }
    }
    float Z = wA * zA + wB * zB;
    float f = (wA * numA + wB * numB) / Z;
    float e2 = f > 0.f ? f : expf(f) - 1.f;
    xcb[(size_t)i * (NHEADS * NHID) + hd * NHID + lane] = f2bf(e2);
  }
}

// ---------------------------------------------------------------------------
// K7: h2 = xc @ Wo via MFMA (M=4096,N=16,K=512) + fused layer-2 scores.
// ---------------------------------------------------------------------------
__global__ __launch_bounds__(256) void k_gemm2(const unsigned short* __restrict__ xcb,
                                               const unsigned short* __restrict__ Wt2,
                                               const float* __restrict__ ao,
                                               float* __restrict__ h2,
                                               float* __restrict__ ssrc,
                                               float* __restrict__ sdst) {
  const int t = threadIdx.x;
  const int w = t >> 6, lane = t & 63;
  const int lr = lane & 15, kg = lane >> 4;
  const int i0 = blockIdx.x * 64 + w * 16;
  f32x4 acc = (f32x4){0.f, 0.f, 0.f, 0.f};
  const unsigned short* arow = xcb + (size_t)(i0 + lr) * NFEAT;
  const unsigned short* brow = Wt2 + (size_t)lr * NFEAT;
#pragma unroll
  for (int k0 = 0; k0 < NFEAT; k0 += 32) {
    bf16x8 af = __builtin_bit_cast(bf16x8, *(const uint4*)(arow + k0 + kg * 8));
    bf16x8 bv = __builtin_bit_cast(bf16x8, *(const uint4*)(brow + k0 + kg * 8));
    acc = __builtin_amdgcn_mfma_f32_16x16x32_bf16(af, bv, acc, 0, 0, 0);
  }
  float aS = ao[lr], aD = ao[16 + lr];
#pragma unroll
  for (int reg = 0; reg < 4; ++reg) {
    int row = i0 + kg * 4 + reg;
    h2[(size_t)row * NCLASS + lr] = acc[reg];
    float ps = acc[reg] * aS, pd = acc[reg] * aD;
#pragma unroll
    for (int m = 1; m < 16; m <<= 1) { ps += __shfl_xor(ps, m); pd += __shfl_xor(pd, m); }
    if (lr == 0) { ssrc[row] = ps; sdst[row] = pd; }
  }
}

// ---------------------------------------------------------------------------
// K8: layer-2 DIRECT attention + ELU + log_softmax. One wave per row; t in
// LDS; h2 rows L2-hot; exact row max via LR(s + tmax); 17-value shfl reduce.
// grid 256 x 1024 thr (16 rows/block).
// ---------------------------------------------------------------------------
__global__ __launch_bounds__(1024) void k_attn2(const float* __restrict__ ssrc,
                                                const float* __restrict__ t,
                                                const float* __restrict__ h2,
                                                float* __restrict__ out) {
  __shared__ float tl[N];  // 16 KB
  int tid = threadIdx.x;
  {
    int i4 = tid * 4;
    float4 v = *(const float4*)(t + i4);
    *(float4*)(tl + i4) = v;
  }
  __syncthreads();
  int w = tid >> 6, lane = tid & 63;
  int i = blockIdx.x * 16 + w;
  // tmax (each wave reduces over all N from LDS)
  float mx = -1e30f;
  for (int j = lane; j < N; j += 64) mx = fmaxf(mx, tl[j]);
#pragma unroll
  for (int m = 32; m; m >>= 1) mx = fmaxf(mx, __shfl_xor(mx, m));
  float s = ssrc[i];
  float vmax = s + mx;
  float rowm = fmaxf(vmax, ALPHA * vmax);  // LeakyReLU monotone -> row max
  float n0 = 0.f, n1 = 0.f, n2 = 0.f, n3 = 0.f, n4 = 0.f, n5 = 0.f, n6 = 0.f, n7 = 0.f;
  float n8 = 0.f, n9 = 0.f, n10 = 0.f, n11 = 0.f, n12 = 0.f, n13 = 0.f, n14 = 0.f, n15 = 0.f;
  float Z = 0.f;
  for (int j = lane; j < N; j += 64) {
    float v = s + tl[j];
    float e = expf(fmaxf(v, ALPHA * v) - rowm);
    Z += e;
    const float4* hr = (const float4*)(h2 + (size_t)j * NCLASS);
    float4 a = hr[0], b = hr[1], c = hr[2], d = hr[3];
    n0 += e * a.x; n1 += e * a.y; n2 += e * a.z; n3 += e * a.w;
    n4 += e * b.x; n5 += e * b.y; n6 += e * b.z; n7 += e * b.w;
    n8 += e * c.x; n9 += e * c.y; n10 += e * c.z; n11 += e * c.w;
    n12 += e * d.x; n13 += e * d.y; n14 += e * d.z; n15 += e * d.w;
  }
#pragma unroll
  for (int m = 32; m; m >>= 1) {
    Z += __shfl_xor(Z, m);
    n0 += __shfl_xor(n0, m); n1 += __shfl_xor(n1, m);
    n2 += __shfl_xor(n2, m); n3 += __shfl_xor(n3, m);
    n4 += __shfl_xor(n4, m); n5 += __shfl_xor(n5, m);
    n6 += __shfl_xor(n6, m); n7 += __shfl_xor(n7, m);
    n8 += __shfl_xor(n8, m); n9 += __shfl_xor(n9, m);
    n10 += __shfl_xor(n10, m); n11 += __shfl_xor(n11, m);
    n12 += __shfl_xor(n12, m); n13 += __shfl_xor(n13, m);
    n14 += __shfl_xor(n14, m); n15 += __shfl_xor(n15, m);
  }
  float rz = 1.f / Z;
  float o[16] = {n0 * rz, n1 * rz, n2 * rz, n3 * rz, n4 * rz, n5 * rz, n6 * rz, n7 * rz,
                 n8 * rz, n9 * rz, n10 * rz, n11 * rz, n12 * rz, n13 * rz, n14 * rz, n15 * rz};
  float omax = -1e30f;
#pragma unroll
  for (int c = 0; c < 16; ++c) {
    o[c] = o[c] > 0.f ? o[c] : expf(o[c]) - 1.f;  // ELU
    omax = fmaxf(omax, o[c]);
  }
  float sum = 0.f;
#pragma unroll
  for (int c = 0; c < 16; ++c) sum += expf(o[c] - omax);
  float lse = omax + logf(sum);
  if (lane < 16) {
    float myo = 0.f;
#pragma unroll
    for (int c = 0; c < 16; ++c) if (lane == c) myo = o[c];  // static select
    out[(size_t)i * NCLASS + lane] = myo - lse;
  }
}

// ---------------------------------------------------------------------------
extern "C" void kernel_launch(void* const* d_in, const int* in_sizes, int n_in,
                              void* d_out, int out_size, void* d_ws, size_t ws_size,
                              hipStream_t stream) {
  const float* x  = (const float*)d_in[0];
  const float* Wh = (const float*)d_in[1];
  const float* ah = (const float*)d_in[2];
  const float* Wo = (const float*)d_in[3];
  const float* ao = (const float*)d_in[4];
  float* out = (float*)d_out;

  char* base = (char*)d_ws;
  size_t off = 0;
  auto alloc_f = [&](size_t n) -> float* {
    float* p = (float*)(base + off);
    off = (off + n * sizeof(float) + 255) & ~(size_t)255;
    return p;
  };
  auto alloc_i = [&](size_t n) -> int* {
    int* p = (int*)(base + off);
    off = (off + n * sizeof(int) + 255) & ~(size_t)255;
    return p;
  };
  auto alloc_u16 = [&](size_t n) -> unsigned short* {
    unsigned short* p = (unsigned short*)(base + off);
    off = (off + n * sizeof(unsigned short) + 255) & ~(size_t)255;
    return p;
  };

  unsigned short* xbf = alloc_u16((size_t)N * NFEAT);
  unsigned short* Wt  = alloc_u16((size_t)NHEADS * NHID * NFEAT);
  unsigned short* Wt2 = alloc_u16((size_t)NCLASS * NFEAT);
  unsigned short* h1b = alloc_u16((size_t)NHEADS * N * NHID);
  float* ssrc1 = alloc_f((size_t)NHEADS * N);
  float* sdst1 = alloc_f((size_t)NHEADS * N);
  float* ts1   = alloc_f((size_t)NHEADS * N);
  int*   perm1 = alloc_i((size_t)NHEADS * N);
  int*   ksp1  = alloc_i((size_t)NHEADS * N);
  float* csA1  = alloc_f((size_t)NHEADS * NC * NHID);
  float* csB1  = alloc_f((size_t)NHEADS * NC * NHID);
  float* csAz1 = alloc_f(NHEADS * NC);
  float* csBz1 = alloc_f(NHEADS * NC);
  unsigned short* xcb = alloc_u16((size_t)N * NHEADS * NHID);
  float* h2    = alloc_f((size_t)N * NCLASS);
  float* ssrc2 = alloc_f(N);
  float* sdst2 = alloc_f(N);

  if (off > ws_size) return;

  hipLaunchKernelGGL(k_pack, dim3(2113), dim3(256), 0, stream, x, Wh, Wo, xbf, Wt, Wt2);

  // ---- Layer 1 ----
  hipLaunchKernelGGL(k_gemm_h, dim3(N / 128, NHEADS), dim3(256), 0, stream, xbf, Wt, ah, h1b, ssrc1, sdst1);
  hipLaunchKernelGGL(k_rank, dim3(64, NHEADS), dim3(256), 0, stream, sdst1, ssrc1, ts1, perm1, ksp1);
  hipLaunchKernelGGL(k_chunksum1, dim3(64, NHEADS), dim3(256), 0, stream, ts1, perm1, h1b, csA1, csB1, csAz1, csBz1);
  hipLaunchKernelGGL(k_chunkscan1, dim3(NHEADS), dim3(1024), 0, stream, csA1, csB1, csAz1, csBz1);
  hipLaunchKernelGGL(k_combine1, dim3(NHEADS * 256), dim3(256), 0, stream, ssrc1, ts1, perm1, ksp1, h1b, csA1, csB1, csAz1, csBz1, xcb);

  // ---- Layer 2 (direct attention) ----
  hipLaunchKernelGGL(k_gemm2, dim3(N / 64), dim3(256), 0, stream, xcb, Wt2, ao, h2, ssrc2, sdst2);
  hipLaunchKernelGGL(k_attn2, dim3(N / 16), dim3(1024), 0, stream, ssrc2, sdst2, h2, out);
}

// Round 11
// 142.838 us; speedup vs baseline: 1.1281x; 1.1281x over previous
//
#include <hip/hip_runtime.h>
#include <math.h>

#define N 4096
#define NFEAT 512
#define NHID 64
#define NCLASS 16
#define NHEADS 8
#define ALPHA 0.2f
#define NC 256   // chunks per head (16 rows each)

typedef __attribute__((ext_vector_type(8))) short bf16x8;
typedef __attribute__((ext_vector_type(4))) float f32x4;

__device__ inline unsigned short f2bf(float f) {
  unsigned u = __float_as_uint(f);
  unsigned r = u + 0x7fffu + ((u >> 16) & 1u);  // RNE
  return (unsigned short)(r >> 16);
}
__device__ inline float bf2f(unsigned short u) {
  return __uint_as_float(((unsigned)u) << 16);
}
__device__ inline unsigned mono(float f) {
  unsigned u = __float_as_uint(f);
  return (u & 0x80000000u) ? ~u : (u | 0x80000000u);
}

// ---------------------------------------------------------------------------
// P0: pack. blocks [0,2048): x->bf16; [2048,2112): Wt=bf16(Wh^T); 2112: Wt2.
// ---------------------------------------------------------------------------
__global__ __launch_bounds__(256) void k_pack(const float* __restrict__ x,
                                              const float* __restrict__ Wh,
                                              const float* __restrict__ Wo,
                                              unsigned short* __restrict__ xb,
                                              unsigned short* __restrict__ Wt,
                                              unsigned short* __restrict__ Wt2) {
  int b = blockIdx.x;
  if (b < 2048) {
    int i = (b * 256 + threadIdx.x) * 4;
    float4 v = *(const float4*)(x + i);
    ushort4 o;
    o.x = f2bf(v.x); o.y = f2bf(v.y); o.z = f2bf(v.z); o.w = f2bf(v.w);
    *(ushort4*)(xb + i) = o;
  } else if (b < 2112) {
    int idx = b - 2048;
    int kt = idx & 7, hd = idx >> 3;
    __shared__ float ld[64][65];
    const float* src = Wh + ((size_t)hd * NFEAT + kt * 64) * NHID;
    int r = threadIdx.x >> 2, c0 = (threadIdx.x & 3) * 16;
#pragma unroll
    for (int j = 0; j < 4; ++j) {
      float4 v = *(const float4*)(src + (size_t)r * NHID + c0 + j * 4);
      ld[r][c0 + j * 4 + 0] = v.x; ld[r][c0 + j * 4 + 1] = v.y;
      ld[r][c0 + j * 4 + 2] = v.z; ld[r][c0 + j * 4 + 3] = v.w;
    }
    __syncthreads();
    int n = threadIdx.x >> 2, kq = threadIdx.x & 3;
    unsigned short tmp[16];
#pragma unroll
    for (int j = 0; j < 16; ++j) tmp[j] = f2bf(ld[kq * 16 + j][n]);
    unsigned short* dst = Wt + ((size_t)hd * 64 + n) * NFEAT + kt * 64 + kq * 16;
    ((uint4*)dst)[0] = *(uint4*)tmp;
    ((uint4*)dst)[1] = *(uint4*)(tmp + 8);
  } else {
    for (int e = threadIdx.x; e < NFEAT * NCLASS; e += 256) {
      int n = e & 15, k = e >> 4;
      Wt2[(size_t)n * NFEAT + k] = f2bf(Wo[(size_t)k * NCLASS + n]);
    }
  }
}

// ---------------------------------------------------------------------------
// K1: MFMA bf16 GEMM h = x @ Wh per head, 128x64 tile, 4 waves, fused scores.
// h stored bf16.
// ---------------------------------------------------------------------------
__global__ __launch_bounds__(256) void k_gemm_h(const unsigned short* __restrict__ xb,
                                                const unsigned short* __restrict__ Wt,
                                                const float* __restrict__ ah,
                                                unsigned short* __restrict__ h1b,
                                                float* __restrict__ ssrc,
                                                float* __restrict__ sdst) {
  const int hd = blockIdx.y;
  const int i0 = blockIdx.x * 128;
  const int t = threadIdx.x;
  const int w = t >> 6, lane = t & 63;
  const int lr = lane & 15, kg = lane >> 4;
  const int wm = (w & 1) * 64, wn = (w >> 1) * 32;
  __shared__ uint4 Als[128][4];
  __shared__ uint4 Bls[64][4];
  __shared__ float sredS[128][2];
  __shared__ float sredD[128][2];
  const unsigned short* xrow = xb + (size_t)i0 * NFEAT;
  const unsigned short* wrow = Wt + (size_t)hd * 64 * NFEAT;

  f32x4 acc[4][2];
#pragma unroll
  for (int a = 0; a < 4; ++a)
#pragma unroll
    for (int b = 0; b < 2; ++b) acc[a][b] = (f32x4){0.f, 0.f, 0.f, 0.f};

  const int ra = t >> 1, ua = (t & 1) * 2;
  const int rb = t >> 2, ub = t & 3;
  for (int k0 = 0; k0 < NFEAT; k0 += 32) {
    uint4 qa0 = *(const uint4*)(xrow + (size_t)ra * NFEAT + k0 + ua * 8);
    uint4 qa1 = *(const uint4*)(xrow + (size_t)ra * NFEAT + k0 + ua * 8 + 8);
    uint4 qb  = *(const uint4*)(wrow + (size_t)rb * NFEAT + k0 + ub * 8);
    Als[ra][(ua) ^ (ra & 3)] = qa0;
    Als[ra][(ua + 1) ^ (ra & 3)] = qa1;
    Bls[rb][ub ^ (rb & 3)] = qb;
    __syncthreads();
    bf16x8 af[4], bfv[2];
#pragma unroll
    for (int mb = 0; mb < 4; ++mb) {
      int row = wm + mb * 16 + lr;
      af[mb] = __builtin_bit_cast(bf16x8, Als[row][kg ^ (row & 3)]);
    }
#pragma unroll
    for (int nb = 0; nb < 2; ++nb) {
      int col = wn + nb * 16 + lr;
      bfv[nb] = __builtin_bit_cast(bf16x8, Bls[col][kg ^ (col & 3)]);
    }
#pragma unroll
    for (int mb = 0; mb < 4; ++mb)
#pragma unroll
      for (int nb = 0; nb < 2; ++nb)
        acc[mb][nb] = __builtin_amdgcn_mfma_f32_16x16x32_bf16(af[mb], bfv[nb], acc[mb][nb], 0, 0, 0);
    __syncthreads();
  }

  unsigned short* hout = h1b + ((size_t)hd * N + i0) * NHID;
#pragma unroll
  for (int mb = 0; mb < 4; ++mb)
#pragma unroll
    for (int nb = 0; nb < 2; ++nb) {
      int rbase = wm + mb * 16 + kg * 4;
      int col = wn + nb * 16 + lr;
#pragma unroll
      for (int reg = 0; reg < 4; ++reg)
        hout[(size_t)(rbase + reg) * NHID + col] = f2bf(acc[mb][nb][reg]);
    }

  float aS[2], aD[2];
#pragma unroll
  for (int nb = 0; nb < 2; ++nb) {
    aS[nb] = ah[hd * 128 + wn + nb * 16 + lr];
    aD[nb] = ah[hd * 128 + 64 + wn + nb * 16 + lr];
  }
#pragma unroll
  for (int mb = 0; mb < 4; ++mb)
#pragma unroll
    for (int reg = 0; reg < 4; ++reg) {
      float ps = acc[mb][0][reg] * aS[0] + acc[mb][1][reg] * aS[1];
      float pd = acc[mb][0][reg] * aD[0] + acc[mb][1][reg] * aD[1];
#pragma unroll
      for (int m = 1; m < 16; m <<= 1) { ps += __shfl_xor(ps, m); pd += __shfl_xor(pd, m); }
      if (lr == 0) {
        int rl = wm + mb * 16 + kg * 4 + reg;
        sredS[rl][w >> 1] = ps;
        sredD[rl][w >> 1] = pd;
      }
    }
  __syncthreads();
  if (t < 128) {
    ssrc[(size_t)hd * N + i0 + t] = sredS[t][0] + sredS[t][1];
    sdst[(size_t)hd * N + i0 + t] = sredD[t][0] + sredD[t][1];
  }
}

// ---------------------------------------------------------------------------
// K4: ballot rank + per-row split-k (layer 1 only). u32 keys.
// ---------------------------------------------------------------------------
__global__ __launch_bounds__(256) void k_rank(const float* __restrict__ t,
                                              const float* __restrict__ ssrc,
                                              float* __restrict__ ts,
                                              int* __restrict__ perm,
                                              int* __restrict__ ksp) {
  int hd = blockIdx.y;
  const float* th = t + (size_t)hd * N;
  __shared__ unsigned skey[N];
  int tid = threadIdx.x;
  for (int i = tid; i < N; i += 256)
    skey[i] = (mono(th[i]) & 0xFFFFF000u) | (unsigned)i;
  __syncthreads();
  int wv = tid >> 6, lane = tid & 63;
  int jbase = blockIdx.x * 64 + wv * 16;
  unsigned kj[16], qk[16];
  int cnt[16], cq[16];
#pragma unroll
  for (int jj = 0; jj < 16; ++jj) {
    kj[jj] = skey[jbase + jj];
    qk[jj] = (mono(-ssrc[(size_t)hd * N + jbase + jj]) & 0xFFFFF000u) | 0xFFFu;
    cnt[jj] = 0; cq[jj] = 0;
  }
  for (int c = 0; c < N; c += 64) {
    unsigned key = skey[c + lane];
#pragma unroll
    for (int jj = 0; jj < 16; ++jj) {
      cnt[jj] += __popcll(__ballot(key < kj[jj]));
      cq[jj]  += __popcll(__ballot(key < qk[jj]));
    }
  }
  int myc = 0, myq = 0;
#pragma unroll
  for (int jj = 0; jj < 16; ++jj)
    if (lane == jj) { myc = cnt[jj]; myq = cq[jj]; }
  if (lane < 16) {
    int j = jbase + lane;
    ts[(size_t)hd * N + myc] = th[j];
    perm[(size_t)hd * N + myc] = j;
    ksp[(size_t)hd * N + j] = myq;
  }
}

// ---------------------------------------------------------------------------
// K5a: chunksum layer 1 (wide grid for the gather). One wave per 16-row
// chunk; grid (64, 8) x 256 thr = 2048 waves.
// ---------------------------------------------------------------------------
__global__ __launch_bounds__(256) void k_chunksum1(const float* __restrict__ ts,
                                                   const int* __restrict__ perm,
                                                   const unsigned short* __restrict__ h1b,
                                                   float* __restrict__ csA,
                                                   float* __restrict__ csB,
                                                   float* __restrict__ csAz,
                                                   float* __restrict__ csBz) {
  int hd = blockIdx.y, lane = threadIdx.x & 63;
  int c = blockIdx.x * 4 + (threadIdx.x >> 6);
  int r0 = c * 16;
  float tm = ts[(size_t)hd * N + N - 1];
  float tvv = ts[(size_t)hd * N + r0 + (lane & 15)];
  float ev = expf((lane < 16 ? ALPHA : 1.f) * (tvv - tm));
  int pvv = perm[(size_t)hd * N + r0 + (lane & 15)];
  float sA = 0.f, sB = 0.f, zA = 0.f, zB = 0.f;
#pragma unroll
  for (int r = 0; r < 16; ++r) {
    float eA = __shfl(ev, r);
    float eB = __shfl(ev, 16 + r);
    int p = __shfl(pvv, r);
    float hv = bf2f(h1b[((size_t)hd * N + p) * NHID + lane]);
    sA += eA * hv; sB += eB * hv; zA += eA; zB += eB;
  }
  csA[((size_t)hd * NC + c) * NHID + lane] = sA;
  csB[((size_t)hd * NC + c) * NHID + lane] = sB;
  if (lane == 0) { csAz[hd * NC + c] = zA; csBz[hd * NC + c] = zB; }
}

// ---------------------------------------------------------------------------
// K5b: scan-only layer 1 (narrow; no gather). 8 blocks x 1024 thr.
// ---------------------------------------------------------------------------
__global__ __launch_bounds__(1024) void k_chunkscan1(float* __restrict__ csA,
                                                     float* __restrict__ csB,
                                                     float* __restrict__ csAz,
                                                     float* __restrict__ csBz) {
  int hd = blockIdx.x;
  int t = threadIdx.x, w = t >> 6, lane = t & 63;
  __shared__ float pA[16][64], pB[16][64];
  __shared__ float pAz[16], pBz[16];
  float rA[16], rB[16], rAz[16], rBz[16];
#pragma unroll
  for (int cc = 0; cc < 16; ++cc) {
    int c = w * 16 + cc;
    rA[cc] = csA[((size_t)hd * NC + c) * NHID + lane];
    rB[cc] = csB[((size_t)hd * NC + c) * NHID + lane];
    rAz[cc] = csAz[hd * NC + c];
    rBz[cc] = csBz[hd * NC + c];
  }
  float tA = 0.f, tB = 0.f, tAz = 0.f, tBz = 0.f;
#pragma unroll
  for (int cc = 0; cc < 16; ++cc) { tA += rA[cc]; tB += rB[cc]; tAz += rAz[cc]; tBz += rBz[cc]; }
  pA[w][lane] = tA; pB[w][lane] = tB;
  if (lane == 0) { pAz[w] = tAz; pBz[w] = tBz; }
  __syncthreads();
  float bA = 0.f, bAz = 0.f, bB = 0.f, bBz = 0.f;
  for (int w2 = 0; w2 < w; ++w2) { bA += pA[w2][lane]; bAz += pAz[w2]; }
  for (int w2 = w + 1; w2 < 16; ++w2) { bB += pB[w2][lane]; bBz += pBz[w2]; }
  float run = bA, runz = bAz;
#pragma unroll
  for (int cc = 0; cc < 16; ++cc) {
    int c = w * 16 + cc;
    csA[((size_t)hd * NC + c) * NHID + lane] = run; run += rA[cc];
    if (lane == 0) csAz[hd * NC + c] = runz;
    runz += rAz[cc];
  }
  run = bB; runz = bBz;
#pragma unroll
  for (int cc = 15; cc >= 0; --cc) {
    int c = w * 16 + cc;
    csB[((size_t)hd * NC + c) * NHID + lane] = run; run += rB[cc];
    if (lane == 0) csBz[hd * NC + c] = runz;
    runz += rBz[cc];
  }
}

// ---------------------------------------------------------------------------
// K6: layer-1 combine. Precomputed split-k; chunk bases + 16-term rebuild.
// ---------------------------------------------------------------------------
__global__ __launch_bounds__(256) void k_combine1(const float* __restrict__ ssrc,
                                                  const float* __restrict__ ts,
                                                  const int* __restrict__ perm,
                                                  const int* __restrict__ ksp,
                                                  const unsigned short* __restrict__ h1b,
                                                  const float* __restrict__ csA,
                                                  const float* __restrict__ csB,
                                                  const float* __restrict__ csAz,
                                                  const float* __restrict__ csBz,
                                                  unsigned short* __restrict__ xcb) {
  int hd = blockIdx.x >> 8;
  int base = (blockIdx.x & 255) * 16;
  int w = threadIdx.x >> 6, lane = threadIdx.x & 63;
  const float* tsh = ts + (size_t)hd * N;
  float tm = tsh[N - 1];
  for (int it = 0; it < 4; ++it) {
    int i = base + w * 4 + it;
    float s = ssrc[(size_t)hd * N + i];
    int k = ksp[(size_t)hd * N + i];
    int c = k >> 4; if (c > NC - 1) c = NC - 1;
    int c0 = c * 16;
    float v = s + tm;
    float m = fmaxf(v, ALPHA * v);
    float wA = expf(ALPHA * v - m), wB = expf(v - m);
    size_t cb = (size_t)hd * NC + c;
    float numA = csA[cb * NHID + lane];
    float numB = csB[cb * NHID + lane];
    float zA = csAz[cb], zB = csBz[cb];
    int r15 = lane & 15;
    float tvv = tsh[c0 + r15];
    int pvv = perm[(size_t)hd * N + c0 + r15];
    float ev = expf(((c0 + r15) < k ? ALPHA : 1.f) * (tvv - tm));
#pragma unroll
    for (int r = 0; r < 16; ++r) {
      float e = __shfl(ev, r);
      int p = __shfl(pvv, r);
      float hv = bf2f(h1b[((size_t)hd * N + p) * NHID + lane]);
      bool isA = (c0 + r) < k;
      if (isA) { numA += e * hv; zA += e; } else { numB += e * hv; zB += e; }
    }
    float Z = wA * zA + wB * zB;
    float f = (wA * numA + wB * numB) / Z;
    float e2 = f > 0.f ? f : expf(f) - 1.f;
    xcb[(size_t)i * (NHEADS * NHID) + hd * NHID + lane] = f2bf(e2);
  }
}

// ---------------------------------------------------------------------------
// K7: h2 = xc @ Wo via MFMA (M=4096,N=16,K=512) + fused layer-2 scores.
// ---------------------------------------------------------------------------
__global__ __launch_bounds__(256) void k_gemm2(const unsigned short* __restrict__ xcb,
                                               const unsigned short* __restrict__ Wt2,
                                               const float* __restrict__ ao,
                                               float* __restrict__ h2,
                                               float* __restrict__ ssrc,
                                               float* __restrict__ sdst) {
  const int t = threadIdx.x;
  const int w = t >> 6, lane = t & 63;
  const int lr = lane & 15, kg = lane >> 4;
  const int i0 = blockIdx.x * 64 + w * 16;
  f32x4 acc = (f32x4){0.f, 0.f, 0.f, 0.f};
  const unsigned short* arow = xcb + (size_t)(i0 + lr) * NFEAT;
  const unsigned short* brow = Wt2 + (size_t)lr * NFEAT;
#pragma unroll
  for (int k0 = 0; k0 < NFEAT; k0 += 32) {
    bf16x8 af = __builtin_bit_cast(bf16x8, *(const uint4*)(arow + k0 + kg * 8));
    bf16x8 bv = __builtin_bit_cast(bf16x8, *(const uint4*)(brow + k0 + kg * 8));
    acc = __builtin_amdgcn_mfma_f32_16x16x32_bf16(af, bv, acc, 0, 0, 0);
  }
  float aS = ao[lr], aD = ao[16 + lr];
#pragma unroll
  for (int reg = 0; reg < 4; ++reg) {
    int row = i0 + kg * 4 + reg;
    h2[(size_t)row * NCLASS + lr] = acc[reg];
    float ps = acc[reg] * aS, pd = acc[reg] * aD;
#pragma unroll
    for (int m = 1; m < 16; m <<= 1) { ps += __shfl_xor(ps, m); pd += __shfl_xor(pd, m); }
    if (lr == 0) { ssrc[row] = ps; sdst[row] = pd; }
  }
}

// ---------------------------------------------------------------------------
// K8: layer-2 direct attention, REGISTER-BLOCKED (R=8 rows/wave) + ELU +
// log_softmax. h2 traffic = (N/8) x 256KB = 128 MB (was 1 GB at R=1).
// grid 256 x 128 thr (2 waves, 16 rows/block).
// ---------------------------------------------------------------------------
__global__ __launch_bounds__(128) void k_attn2(const float* __restrict__ ssrc,
                                               const float* __restrict__ t,
                                               const float* __restrict__ h2,
                                               float* __restrict__ out) {
  __shared__ float tl[N];  // 16 KB
  int tid = threadIdx.x;
#pragma unroll
  for (int rep = 0; rep < 8; ++rep) {
    int i4 = (rep * 128 + tid) * 4;
    *(float4*)(tl + i4) = *(const float4*)(t + i4);
  }
  __syncthreads();
  int w = tid >> 6, lane = tid & 63;
  int i0 = blockIdx.x * 16 + w * 8;
  // tmax from LDS
  float mx = -1e30f;
  for (int j = lane; j < N; j += 64) mx = fmaxf(mx, tl[j]);
#pragma unroll
  for (int m = 32; m; m >>= 1) mx = fmaxf(mx, __shfl_xor(mx, m));
  float s[8], rowm[8], Z[8];
  float num[8][16];
#pragma unroll
  for (int r = 0; r < 8; ++r) {
    s[r] = ssrc[i0 + r];
    float v = s[r] + mx;
    rowm[r] = fmaxf(v, ALPHA * v);  // LeakyReLU monotone -> exact row max
    Z[r] = 0.f;
#pragma unroll
    for (int c = 0; c < 16; ++c) num[r][c] = 0.f;
  }
  for (int j = lane; j < N; j += 64) {
    float tj = tl[j];
    const float4* hr = (const float4*)(h2 + (size_t)j * NCLASS);
    float4 a = hr[0], b = hr[1], c4 = hr[2], d = hr[3];
#pragma unroll
    for (int r = 0; r < 8; ++r) {
      float v = s[r] + tj;
      float e = expf(fmaxf(v, ALPHA * v) - rowm[r]);
      Z[r] += e;
      num[r][0]  += e * a.x;  num[r][1]  += e * a.y;
      num[r][2]  += e * a.z;  num[r][3]  += e * a.w;
      num[r][4]  += e * b.x;  num[r][5]  += e * b.y;
      num[r][6]  += e * b.z;  num[r][7]  += e * b.w;
      num[r][8]  += e * c4.x; num[r][9]  += e * c4.y;
      num[r][10] += e * c4.z; num[r][11] += e * c4.w;
      num[r][12] += e * d.x;  num[r][13] += e * d.y;
      num[r][14] += e * d.z;  num[r][15] += e * d.w;
    }
  }
  // full 64-lane butterfly: every lane ends with the totals
#pragma unroll
  for (int m = 32; m; m >>= 1) {
#pragma unroll
    for (int r = 0; r < 8; ++r) {
      Z[r] += __shfl_xor(Z[r], m);
#pragma unroll
      for (int c = 0; c < 16; ++c) num[r][c] += __shfl_xor(num[r][c], m);
    }
  }
  int cl = lane & 15;
#pragma unroll
  for (int r = 0; r < 8; ++r) {
    float rz = 1.f / Z[r];
    float ov = 0.f;
#pragma unroll
    for (int c = 0; c < 16; ++c) if (cl == c) ov = num[r][c];  // static select
    ov *= rz;
    ov = ov > 0.f ? ov : expf(ov) - 1.f;  // ELU
    float mo = ov;
#pragma unroll
    for (int mk = 1; mk < 16; mk <<= 1) mo = fmaxf(mo, __shfl_xor(mo, mk, 16));
    float sum = expf(ov - mo);
#pragma unroll
    for (int mk = 1; mk < 16; mk <<= 1) sum += __shfl_xor(sum, mk, 16);
    if (lane < 16) out[(size_t)(i0 + r) * NCLASS + lane] = ov - mo - logf(sum);
  }
}

// ---------------------------------------------------------------------------
extern "C" void kernel_launch(void* const* d_in, const int* in_sizes, int n_in,
                              void* d_out, int out_size, void* d_ws, size_t ws_size,
                              hipStream_t stream) {
  const float* x  = (const float*)d_in[0];
  const float* Wh = (const float*)d_in[1];
  const float* ah = (const float*)d_in[2];
  const float* Wo = (const float*)d_in[3];
  const float* ao = (const float*)d_in[4];
  float* out = (float*)d_out;

  char* base = (char*)d_ws;
  size_t off = 0;
  auto alloc_f = [&](size_t n) -> float* {
    float* p = (float*)(base + off);
    off = (off + n * sizeof(float) + 255) & ~(size_t)255;
    return p;
  };
  auto alloc_i = [&](size_t n) -> int* {
    int* p = (int*)(base + off);
    off = (off + n * sizeof(int) + 255) & ~(size_t)255;
    return p;
  };
  auto alloc_u16 = [&](size_t n) -> unsigned short* {
    unsigned short* p = (unsigned short*)(base + off);
    off = (off + n * sizeof(unsigned short) + 255) & ~(size_t)255;
    return p;
  };

  unsigned short* xbf = alloc_u16((size_t)N * NFEAT);
  unsigned short* Wt  = alloc_u16((size_t)NHEADS * NHID * NFEAT);
  unsigned short* Wt2 = alloc_u16((size_t)NCLASS * NFEAT);
  unsigned short* h1b = alloc_u16((size_t)NHEADS * N * NHID);
  float* ssrc1 = alloc_f((size_t)NHEADS * N);
  float* sdst1 = alloc_f((size_t)NHEADS * N);
  float* ts1   = alloc_f((size_t)NHEADS * N);
  int*   perm1 = alloc_i((size_t)NHEADS * N);
  int*   ksp1  = alloc_i((size_t)NHEADS * N);
  float* csA1  = alloc_f((size_t)NHEADS * NC * NHID);
  float* csB1  = alloc_f((size_t)NHEADS * NC * NHID);
  float* csAz1 = alloc_f(NHEADS * NC);
  float* csBz1 = alloc_f(NHEADS * NC);
  unsigned short* xcb = alloc_u16((size_t)N * NHEADS * NHID);
  float* h2    = alloc_f((size_t)N * NCLASS);
  float* ssrc2 = alloc_f(N);
  float* sdst2 = alloc_f(N);

  if (off > ws_size) return;

  hipLaunchKernelGGL(k_pack, dim3(2113), dim3(256), 0, stream, x, Wh, Wo, xbf, Wt, Wt2);

  // ---- Layer 1 ----
  hipLaunchKernelGGL(k_gemm_h, dim3(N / 128, NHEADS), dim3(256), 0, stream, xbf, Wt, ah, h1b, ssrc1, sdst1);
  hipLaunchKernelGGL(k_rank, dim3(64, NHEADS), dim3(256), 0, stream, sdst1, ssrc1, ts1, perm1, ksp1);
  hipLaunchKernelGGL(k_chunksum1, dim3(64, NHEADS), dim3(256), 0, stream, ts1, perm1, h1b, csA1, csB1, csAz1, csBz1);
  hipLaunchKernelGGL(k_chunkscan1, dim3(NHEADS), dim3(1024), 0, stream, csA1, csB1, csAz1, csBz1);
  hipLaunchKernelGGL(k_combine1, dim3(NHEADS * 256), dim3(256), 0, stream, ssrc1, ts1, perm1, ksp1, h1b, csA1, csB1, csAz1, csBz1, xcb);

  // ---- Layer 2 (direct attention, register-blocked) ----
  hipLaunchKernelGGL(k_gemm2, dim3(N / 64), dim3(256), 0, stream, xcb, Wt2, ao, h2, ssrc2, sdst2);
  hipLaunchKernelGGL(k_attn2, dim3(N / 16), dim3(128), 0, stream, ssrc2, sdst2, h2, out);
}